// Round 3
// baseline (1108.149 us; speedup 1.0000x reference)
//
#include <hip/hip_runtime.h>
#include <cstdint>
#include <cstddef>

// CrossAttention1d: N=4, C=512, S=2048, CTX=512, S2=2048, H=8
// R9: diagnostic + T5. flash split into 2 dispatches over qt (grid 16,8,4
// each; still 512 blocks = 2/CU) so the rocprof top-5 table reveals the true
// duration of the largest NON-flash kernel (previously masked by 5 copies of
// flash@196). Also s_setprio(1) around flash MFMA clusters (T5, m191 +4-7%).
// qkv (R7) and gemm_out (R8) unchanged.

#define NB 4
#define CC 512
#define SS 2048
#define HH 8
#define QK_SCALE 0.044194173824159216f  // 512^-0.5

typedef float  floatx4 __attribute__((ext_vector_type(4)));
typedef __bf16 bf16x8  __attribute__((ext_vector_type(8)));
typedef __bf16 bf16x4  __attribute__((ext_vector_type(4)));

__device__ __forceinline__ void async16(const void* g, void* l) {
  __builtin_amdgcn_global_load_lds((const __attribute__((address_space(1))) void*)g,
                                   (__attribute__((address_space(3))) void*)l, 16, 0, 0);
}

// DPP 16-lane row reductions (VALU pipe, not LDS). row_ror:n ctrl = 0x120+n.
template <int N>
__device__ __forceinline__ float dpp_ror_f(float v) {
  return __builtin_bit_cast(
      float, __builtin_amdgcn_update_dpp(0, __builtin_bit_cast(int, v), 0x120 + N, 0xf, 0xf, true));
}
__device__ __forceinline__ float red_max16(float v) {
  v = fmaxf(v, dpp_ror_f<8>(v));
  v = fmaxf(v, dpp_ror_f<4>(v));
  v = fmaxf(v, dpp_ror_f<2>(v));
  v = fmaxf(v, dpp_ror_f<1>(v));
  return v;
}
__device__ __forceinline__ float red_sum16(float v) {
  v += dpp_ror_f<8>(v);
  v += dpp_ror_f<4>(v);
  v += dpp_ror_f<2>(v);
  v += dpp_ror_f<1>(v);
  return v;
}

// ---------------- fused: LN partial stats (blocks 0..511) + weight casts ----------------
__global__ void prep1(const float* __restrict__ x, float* __restrict__ part,
                      const float* __restrict__ Wq, __bf16* __restrict__ WqB,
                      const float* __restrict__ Wkv, __bf16* __restrict__ WkvB,
                      const float* __restrict__ Wo, __bf16* __restrict__ WoB) {
  const int bx = blockIdx.x;
  if (bx < 512) {
    const int n = bx >> 7, cidx = bx & 127;
    const float* p = x + (size_t)n * (CC * SS) + (size_t)cidx * 8192;
    float s = 0.f, q = 0.f;
    for (int j = 0; j < 8; ++j) {
      floatx4 v = *(const floatx4*)&p[(j * 256 + threadIdx.x) * 4];
      for (int e = 0; e < 4; ++e) { s += v[e]; q += v[e] * v[e]; }
    }
    for (int off = 32; off >= 1; off >>= 1) {
      s += __shfl_down(s, off, 64);
      q += __shfl_down(q, off, 64);
    }
    __shared__ float shS[4], shQ[4];
    const int wave = threadIdx.x >> 6, lane = threadIdx.x & 63;
    if (lane == 0) { shS[wave] = s; shQ[wave] = q; }
    __syncthreads();
    if (threadIdx.x == 0) {
      part[bx * 2] = shS[0] + shS[1] + shS[2] + shS[3];
      part[bx * 2 + 1] = shQ[0] + shQ[1] + shQ[2] + shQ[3];
    }
  } else {
    const int r = bx - 512;
    const int y = r >> 12, xb = r & 4095;
    const float* s = y == 0 ? Wq : (y == 1 ? Wkv : Wo);
    __bf16* d = y == 0 ? WqB : (y == 1 ? WkvB : WoB);
    const int cnt = y == 1 ? 1048576 : 524288;
    int idx = xb * 256 + threadIdx.x;
    if (idx >= cnt) return;
    floatx4 v = ((const floatx4*)s)[idx];
    bf16x4 pk;
    for (int e = 0; e < 4; ++e) pk[e] = (__bf16)v[e];
    ((bf16x4*)d)[idx] = pk;
  }
}

__global__ void ln_final(const float* __restrict__ part, float* __restrict__ muA,
                         float* __restrict__ rsA) {
  const int n = blockIdx.x, tid = threadIdx.x;
  float s = part[(n * 128 + tid) * 2];
  float q = part[(n * 128 + tid) * 2 + 1];
  for (int off = 32; off >= 1; off >>= 1) {
    s += __shfl_down(s, off, 64);
    q += __shfl_down(q, off, 64);
  }
  __shared__ float shS[2], shQ[2];
  const int wave = tid >> 6, lane = tid & 63;
  if (lane == 0) { shS[wave] = s; shQ[wave] = q; }
  __syncthreads();
  if (tid == 0) {
    float S = shS[0] + shS[1], Q = shQ[0] + shQ[1];
    const float inv = 1.f / (float)(CC * SS);
    float m = S * inv;
    float v = Q * inv - m * m;
    muA[n] = m;
    rsA[n] = rsqrtf(v + 1e-5f);
  }
}

// ---------------- fused normalize+transpose (input) / transpose (context) ----------------
__global__ void transpose_nc(const float* __restrict__ input, const float* __restrict__ context,
                             __bf16* __restrict__ xnT, __bf16* __restrict__ ctxT,
                             const float* __restrict__ mu, const float* __restrict__ rstd,
                             const float* __restrict__ gamma, const float* __restrict__ beta) {
  __shared__ float t[32][33];
  const int n = blockIdx.z >> 1, which = blockIdx.z & 1;
  const int c0 = blockIdx.y * 32, s0 = blockIdx.x * 32;
  const float* inp = (which ? context : input) + (size_t)n * CC * SS;
  __bf16* op = (which ? ctxT : xnT) + (size_t)n * SS * CC;
  const float muv = which ? 0.f : mu[n];
  const float rs = which ? 1.f : rstd[n];
  for (int i = 0; i < 4; ++i) {
    int c = c0 + threadIdx.y + i * 8;
    float x = inp[(size_t)c * SS + s0 + threadIdx.x];
    if (!which) x = (x - muv) * rs * gamma[c] + beta[c];
    t[threadIdx.y + i * 8][threadIdx.x] = x;
  }
  __syncthreads();
  for (int i = 0; i < 4; ++i) {
    int s = s0 + threadIdx.y + i * 8;
    op[(size_t)s * CC + c0 + threadIdx.x] = (__bf16)t[threadIdx.x][threadIdx.y + i * 8];
  }
}

// ---------------- fused QKV GEMM: 256x256 tile, BK=64, 8 waves, deep pipeline ----------------
// A (row-major, lda=512): WqB (4096x512) or WkvB (8192x512).
// Bt (row-major, ldb=512): xnT or ctxT (s-major, 2048x512).
// C(256x256) per block; wave (wr,wc) owns 128(M) x 64(N).
__global__ void __launch_bounds__(512, 2) gemm_qkv(const __bf16* __restrict__ WqB,
                                                   const __bf16* __restrict__ WkvB,
                                                   const __bf16* __restrict__ xnT,
                                                   const __bf16* __restrict__ ctxT,
                                                   const float* __restrict__ bq,
                                                   const float* __restrict__ bkv,
                                                   __bf16* __restrict__ qT,
                                                   __bf16* __restrict__ kT,
                                                   __bf16* __restrict__ vv) {
  // LDS: A dbuf 2x(256x64) bf16 = 64KB, B dbuf = 64KB; epilogue transpose
  // buffer [256][264] bf16 = 135168B aliases the whole thing (max).
  __shared__ __align__(16) char smem[256 * 264 * 2];
  __bf16* lA = (__bf16*)smem;                  // [2][256*64]
  __bf16* lB = (__bf16*)(smem + 65536);        // [2][256*64]
  __bf16* lT = (__bf16*)smem;                  // [256][264]

  const int n = blockIdx.z, xb = blockIdx.x;
  const int n0 = blockIdx.y * 256;
  const bool isq = xb < 16;
  const int m0 = (isq ? xb : xb - 16) * 256;
  const __bf16* Aw = isq ? WqB : WkvB;
  const __bf16* Bt = (isq ? xnT : ctxT) + (size_t)n * SS * CC;
  const float* bias = isq ? bq : bkv;

  const int tid = threadIdx.x;
  const int wave = tid >> 6, lane = tid & 63;
  const int colv = lane & 15, g = lane >> 4;
  const int wr = wave >> 2, wc = wave & 3;   // 2(M) x 4(N) wave grid
  const int lrow = lane >> 3, lch = lane & 7;

  // stage K-tile t (64 channels) into buffer buf: 8 async16 per wave.
  auto stage = [&](int t, int buf) {
    const int k0 = t * 64;
    __bf16* dA = lA + buf * (256 * 64);
    __bf16* dB = lB + buf * (256 * 64);
#pragma unroll
    for (int j = 0; j < 4; ++j) {
      int r = wave * 32 + j * 8 + lrow;
      int ch = lch ^ (r & 7);
      async16(Aw + (size_t)(m0 + r) * 512 + k0 + ch * 8, dA + (wave * 32 + j * 8) * 64);
      async16(Bt + (size_t)(n0 + r) * 512 + k0 + ch * 8, dB + (wave * 32 + j * 8) * 64);
    }
  };

  floatx4 acc[8][4];
#pragma unroll
  for (int mf = 0; mf < 8; ++mf)
#pragma unroll
    for (int nf = 0; nf < 4; ++nf) acc[mf][nf] = (floatx4)0.f;

  // prologue: tiles 0,1 in flight; wait tile 0 landed (tile 1's 8 stay out).
  stage(0, 0);
  stage(1, 1);
  asm volatile("s_waitcnt vmcnt(8)" ::: "memory");
  __builtin_amdgcn_s_barrier();

  for (int t = 0; t < 8; ++t) {
    const int buf = t & 1;
    const __bf16* cA = lA + buf * (256 * 64);
    const __bf16* cB = lB + buf * (256 * 64);
#pragma unroll
    for (int c = 0; c < 2; ++c) {  // K-half (channels c*32..c*32+31)
      bf16x8 bfr[4], af[4];
      // phase A: B frags + A frags rows 0..63 of this wave's half
#pragma unroll
      for (int nf = 0; nf < 4; ++nf) {
        int rb = wc * 64 + nf * 16 + colv;
        bfr[nf] = *(const bf16x8*)&cB[rb * 64 + (((c * 4 + g) ^ (rb & 7)) << 3)];
      }
#pragma unroll
      for (int mf = 0; mf < 4; ++mf) {
        int ra = wr * 128 + mf * 16 + colv;
        af[mf] = *(const bf16x8*)&cA[ra * 64 + (((c * 4 + g) ^ (ra & 7)) << 3)];
      }
      __builtin_amdgcn_s_barrier();
      __builtin_amdgcn_s_setprio(1);
#pragma unroll
      for (int mf = 0; mf < 4; ++mf)
#pragma unroll
        for (int nf = 0; nf < 4; ++nf)
          acc[mf][nf] =
              __builtin_amdgcn_mfma_f32_16x16x32_bf16(af[mf], bfr[nf], acc[mf][nf], 0, 0, 0);
      __builtin_amdgcn_s_setprio(0);
      __builtin_amdgcn_s_barrier();
      // phase B: A frags rows 64..127 of this wave's half
#pragma unroll
      for (int mf = 0; mf < 4; ++mf) {
        int ra = wr * 128 + 64 + mf * 16 + colv;
        af[mf] = *(const bf16x8*)&cA[ra * 64 + (((c * 4 + g) ^ (ra & 7)) << 3)];
      }
      __builtin_amdgcn_s_barrier();
      __builtin_amdgcn_s_setprio(1);
#pragma unroll
      for (int mf = 0; mf < 4; ++mf)
#pragma unroll
        for (int nf = 0; nf < 4; ++nf)
          acc[mf + 4][nf] =
              __builtin_amdgcn_mfma_f32_16x16x32_bf16(af[mf], bfr[nf], acc[mf + 4][nf], 0, 0, 0);
      __builtin_amdgcn_s_setprio(0);
      __builtin_amdgcn_s_barrier();
    }
    // tile boundary: all waves past trailing barrier => buf's reads retired.
    if (t < 6) {
      stage(t + 2, buf);
      asm volatile("s_waitcnt vmcnt(8)" ::: "memory");  // tile t+1 landed
    } else {
      asm volatile("s_waitcnt vmcnt(0)" ::: "memory");
    }
    __builtin_amdgcn_s_barrier();
  }

  // ---------------- epilogue ----------------
  if (isq || m0 < 4096) {
    // Q / K: transposed store dst[(n0+nl)*4096 + m0+ml] via LDS [256][264]
    __bf16* dst = (isq ? qT : kT) + (size_t)n * SS * 4096;
#pragma unroll
    for (int mf = 0; mf < 8; ++mf) {
      int mb = wr * 128 + mf * 16 + g * 4;
      floatx4 bv = *(const floatx4*)&bias[m0 + mb];
#pragma unroll
      for (int nf = 0; nf < 4; ++nf) {
        int nl = wc * 64 + nf * 16 + colv;
        bf16x4 pk;
#pragma unroll
        for (int i = 0; i < 4; ++i) pk[i] = (__bf16)(acc[mf][nf][i] + bv[i]);
        *(bf16x4*)&lT[nl * 264 + mb] = pk;
      }
    }
    asm volatile("s_waitcnt lgkmcnt(0)" ::: "memory");  // ds_writes visible
    __builtin_amdgcn_s_barrier();
#pragma unroll
    for (int p = 0; p < 16; ++p) {
      int row = p * 16 + (tid >> 5);
      int ch = tid & 31;
      bf16x8 v = *(const bf16x8*)&lT[row * 264 + ch * 8];
      *(bf16x8*)&dst[(size_t)(n0 + row) * 4096 + m0 + ch * 8] = v;
    }
  } else {
    // V: channel-major direct store vn[o*SS + s]
    __bf16* vn = vv + (size_t)n * 4096 * SS;
#pragma unroll
    for (int mf = 0; mf < 8; ++mf) {
      int mb = wr * 128 + mf * 16 + g * 4;
      int o = m0 + mb - 4096;
      floatx4 bv = *(const floatx4*)&bias[m0 + mb];
#pragma unroll
      for (int nf = 0; nf < 4; ++nf) {
        int s = n0 + wc * 64 + nf * 16 + colv;
#pragma unroll
        for (int i = 0; i < 4; ++i)
          vn[(size_t)(o + i) * SS + s] = (__bf16)(acc[mf][nf][i] + bv[i]);
      }
    }
  }
}

// ---------------- flash attention (PV d-split, DPP softmax, staged prefetch) ----------------
__global__ void __launch_bounds__(256) flash_attn(const __bf16* __restrict__ qT,
                                                  const __bf16* __restrict__ kT,
                                                  const __bf16* __restrict__ vv,
                                                  __bf16* __restrict__ yT, int qt0) {
  const int n = blockIdx.z, h = blockIdx.y, qt = blockIdx.x + qt0;
  const int tid = threadIdx.x;
  const int wave = tid >> 6, lane = tid & 63;
  const int colv = lane & 15, g = lane >> 4;

  const __bf16* qTn = qT + (size_t)n * SS * 4096;
  const __bf16* kTn = kT + (size_t)n * SS * 4096;
  const __bf16* vn  = vv + (size_t)n * 4096 * SS;
  __bf16* yTn = yT + (size_t)n * SS * 4096;

  const int qrow0 = qt * 64 + wave * 16;

  __shared__ __bf16 kbuf[32 * 512];
  __shared__ __bf16 vbuf[512 * 32];
  __shared__ __bf16 pbuf[4 * 16 * 88];
  __shared__ float axs[64];
  __shared__ float ils[64];

  bf16x8 qf[16];
  {
    const __bf16* qp = qTn + (size_t)(qrow0 + colv) * 4096 + h * 512 + g * 8;
#pragma unroll
    for (int kc = 0; kc < 16; ++kc) qf[kc] = *(const bf16x8*)(qp + kc * 32);
  }

  floatx4 Oacc[32];
#pragma unroll
  for (int t = 0; t < 32; ++t) Oacc[t] = (floatx4)0.f;
  float mrun[4] = {-1e30f, -1e30f, -1e30f, -1e30f};
  float lrun[4] = {0.f, 0.f, 0.f, 0.f};

  __bf16* pb = pbuf + wave * (16 * 88);

  auto stageK = [&](int kt) {
    const int key0 = kt * 32;
#pragma unroll
    for (int j = 0; j < 8; ++j) {
      int row = wave * 8 + j;
      const __bf16* src = kTn + (size_t)(key0 + row) * 4096 + h * 512 + ((lane ^ (row & 7)) << 3);
      async16(src, &kbuf[row * 512]);
    }
  };
  auto stageV = [&](int kt) {
    const int key0 = kt * 32;
#pragma unroll
    for (int j = 0; j < 8; ++j) {
      int i = wave * 8 + j;
      int row = i * 16 + (lane >> 2);
      int ch = (lane & 3) ^ (row & 3);
      const __bf16* src = vn + (size_t)(h * 512 + row) * SS + key0 + ch * 8;
      async16(src, &vbuf[i * 16 * 32]);
    }
  };

  stageK(0);
  stageV(0);

  for (int kt = 0; kt < 64; ++kt) {
    __syncthreads();  // staged K/V drained & visible

    floatx4 sc[2];
    sc[0] = (floatx4)0.f;
    sc[1] = (floatx4)0.f;
    __builtin_amdgcn_s_setprio(1);
#pragma unroll
    for (int ct = 0; ct < 2; ++ct) {
      int key = ct * 16 + colv;
      const __bf16* kb = &kbuf[key * 512];
      int sw = key & 7;
#pragma unroll
      for (int kc = 0; kc < 16; ++kc) {
        bf16x8 bfr = *(const bf16x8*)(kb + (((kc * 4 + g) ^ sw) << 3));
        sc[ct] = __builtin_amdgcn_mfma_f32_16x16x32_bf16(qf[kc], bfr, sc[ct], 0, 0, 0);
      }
    }
    __builtin_amdgcn_s_setprio(0);

    float p[2][4], alpha[4];
#pragma unroll
    for (int i = 0; i < 4; ++i) {
      float mx = red_max16(fmaxf(sc[0][i], sc[1][i]));
      float mnew = fmaxf(mrun[i], mx * QK_SCALE);
      alpha[i] = __expf(mrun[i] - mnew);
      float rs = 0.f;
#pragma unroll
      for (int ct = 0; ct < 2; ++ct) {
        float pvv = __expf(sc[ct][i] * QK_SCALE - mnew);
        p[ct][i] = pvv;
        rs += pvv;
      }
      rs = red_sum16(rs);
      lrun[i] = lrun[i] * alpha[i] + rs;
      mrun[i] = mnew;
    }
#pragma unroll
    for (int ct = 0; ct < 2; ++ct)
#pragma unroll
      for (int i = 0; i < 4; ++i)
        pb[(g * 4 + i) * 88 + ct * 16 + colv] = (__bf16)p[ct][i];
    if (colv == 0) {
      floatx4 av;
#pragma unroll
      for (int i = 0; i < 4; ++i) av[i] = alpha[i];
      *(floatx4*)&axs[wave * 16 + g * 4] = av;
    }
    __syncthreads();  // P + alpha ready; kbuf reads done

    if (kt < 63) stageK(kt + 1);  // kbuf free during PV

#pragma unroll
    for (int qt4 = 0; qt4 < 4; ++qt4) {
      floatx4 av = *(const floatx4*)&axs[qt4 * 16 + g * 4];
#pragma unroll
      for (int dt = 0; dt < 8; ++dt) {
        floatx4 o = Oacc[qt4 * 8 + dt];
#pragma unroll
        for (int i = 0; i < 4; ++i) o[i] *= av[i];
        Oacc[qt4 * 8 + dt] = o;
      }
    }
    bf16x8 pa[4];
#pragma unroll
    for (int qt4 = 0; qt4 < 4; ++qt4)
      pa[qt4] = *(const bf16x8*)&pbuf[qt4 * (16 * 88) + colv * 88 + g * 8];
    __builtin_amdgcn_s_setprio(1);
#pragma unroll
    for (int dt = 0; dt < 8; ++dt) {
      int drow = wave * 128 + dt * 16 + colv;
      bf16x8 vb = *(const bf16x8*)&vbuf[drow * 32 + ((g ^ (drow & 3)) << 3)];
#pragma unroll
      for (int qt4 = 0; qt4 < 4; ++qt4)
        Oacc[qt4 * 8 + dt] = __builtin_amdgcn_mfma_f32_16x16x32_bf16(pa[qt4], vb,
                                                                    Oacc[qt4 * 8 + dt], 0, 0, 0);
    }
    __builtin_amdgcn_s_setprio(0);
    __syncthreads();  // PV reads done -> vbuf free
    if (kt < 63) stageV(kt + 1);
  }

  if (colv == 0) {
    floatx4 lv;
#pragma unroll
    for (int i = 0; i < 4; ++i) lv[i] = 1.f / lrun[i];
    *(floatx4*)&ils[wave * 16 + g * 4] = lv;
  }
  __syncthreads();
#pragma unroll
  for (int qt4 = 0; qt4 < 4; ++qt4) {
    floatx4 lv = *(const floatx4*)&ils[qt4 * 16 + g * 4];
#pragma unroll
    for (int dt = 0; dt < 8; ++dt)
#pragma unroll
      for (int i = 0; i < 4; ++i) {
        size_t idx = (size_t)(qt * 64 + qt4 * 16 + g * 4 + i) * 4096 + h * 512 + wave * 128 +
                     dt * 16 + colv;
        yTn[idx] = (__bf16)(Oacc[qt4 * 8 + dt][i] * lv[i]);
      }
  }
}

// ---------------- fused out GEMM: out[c][s] = input + bo[c] + Wo·y ----------------
// A = WoB (M=512=c rows, K=4096), Bt = yT (N=2048=s rows, K=4096).
// 128(c) x 128(s) tile, grid (4,16,4)=256 blocks (1/CU), 512 threads
// (8 waves 2x4, each 64x32), BK=64, triple-buffered LDS (96KB), counted
// vmcnt at boundaries, stores s-contiguous fp32 with residual+bias epilogue.
__global__ void __launch_bounds__(512) gemm_out_fused(const __bf16* __restrict__ Wo,
                                                      const __bf16* __restrict__ yT,
                                                      const float* __restrict__ bo,
                                                      const float* __restrict__ input,
                                                      float* __restrict__ out) {
  __shared__ __bf16 lA[3][128 * 64], lB[3][128 * 64];  // 96 KB
  const int n = blockIdx.z;
  const int m0 = blockIdx.x * 128, n0 = blockIdx.y * 128;
  const __bf16* Bt = yT + (size_t)n * SS * 4096;
  const int tid = threadIdx.x;
  const int wave = tid >> 6, lane = tid & 63;
  const int colv = lane & 15, g = lane >> 4;
  const int wr = wave >> 2, wc = wave & 3;   // 2(M) x 4(N); wave-tile 64x32
  const int lrow = lane >> 3, lch = lane & 7;

  // stage K-tile t: per wave 2 async16 for A + 2 for B (4 vmcnt ticks).
  auto stage = [&](int t, int buf) {
    const int k0 = t * 64;
#pragma unroll
    for (int j = 0; j < 2; ++j) {
      int r = wave * 16 + j * 8 + lrow;
      int ch = lch ^ (r & 7);
      async16(Wo + (size_t)(m0 + r) * 4096 + k0 + ch * 8, &lA[buf][(wave * 16 + j * 8) * 64]);
      async16(Bt + (size_t)(n0 + r) * 4096 + k0 + ch * 8, &lB[buf][(wave * 16 + j * 8) * 64]);
    }
  };

  floatx4 acc[4][2];
#pragma unroll
  for (int mt = 0; mt < 4; ++mt)
#pragma unroll
    for (int nt = 0; nt < 2; ++nt) acc[mt][nt] = (floatx4)0.f;

  // prologue: 3 tiles in flight; wait tile 0 landed (8 newer stay out).
  stage(0, 0);
  stage(1, 1);
  stage(2, 2);
  asm volatile("s_waitcnt vmcnt(8)" ::: "memory");
  __builtin_amdgcn_s_barrier();

  int buf = 0;
  for (int t = 0; t < 64; ++t) {
#pragma unroll
    for (int c = 0; c < 2; ++c) {  // K-half (channels c*32..c*32+31)
      bf16x8 af[4], bf[2];
#pragma unroll
      for (int mt = 0; mt < 4; ++mt) {
        int ra = wr * 64 + mt * 16 + colv;
        af[mt] = *(const bf16x8*)&lA[buf][ra * 64 + (((c * 4 + g) ^ (ra & 7)) << 3)];
      }
#pragma unroll
      for (int nt = 0; nt < 2; ++nt) {
        int rb = wc * 32 + nt * 16 + colv;
        bf[nt] = *(const bf16x8*)&lB[buf][rb * 64 + (((c * 4 + g) ^ (rb & 7)) << 3)];
      }
#pragma unroll
      for (int mt = 0; mt < 4; ++mt)
#pragma unroll
        for (int nt = 0; nt < 2; ++nt)
          acc[mt][nt] =
              __builtin_amdgcn_mfma_f32_16x16x32_bf16(af[mt], bf[nt], acc[mt][nt], 0, 0, 0);
    }
    if (t == 63) break;
    __builtin_amdgcn_s_barrier();  // all reads of buf retired
    if (t < 61) {
      stage(t + 3, buf);           // refill freed buf
      asm volatile("s_waitcnt vmcnt(8)" ::: "memory");  // tile t+1 landed
    } else if (t == 61) {
      asm volatile("s_waitcnt vmcnt(4)" ::: "memory");
    } else {  // t == 62
      asm volatile("s_waitcnt vmcnt(0)" ::: "memory");
    }
    __builtin_amdgcn_s_barrier();  // everyone's t+1 landed
    buf = (buf == 2) ? 0 : buf + 1;
  }

  // epilogue: c = m0+wr*64+mt*16+g*4+i ; s = n0+wc*32+nt*16+colv ; fp32 direct
#pragma unroll
  for (int mt = 0; mt < 4; ++mt) {
#pragma unroll
    for (int i = 0; i < 4; ++i) {
      int c = m0 + wr * 64 + mt * 16 + g * 4 + i;
      float bov = bo[c];
      size_t rowb = ((size_t)n * CC + c) * SS;
#pragma unroll
      for (int nt = 0; nt < 2; ++nt) {
        int s = n0 + wc * 32 + nt * 16 + colv;
        out[rowb + s] = acc[mt][nt][i] + bov + input[rowb + s];
      }
    }
  }
}

// ---------------- host launcher ----------------
extern "C" void kernel_launch(void* const* d_in, const int* in_sizes, int n_in,
                              void* d_out, int out_size, void* d_ws, size_t ws_size,
                              hipStream_t stream) {
  const float* input   = (const float*)d_in[0];
  const float* context = (const float*)d_in[1];
  const float* gamma   = (const float*)d_in[2];
  const float* beta    = (const float*)d_in[3];
  const float* Wq      = (const float*)d_in[4];
  const float* bq      = (const float*)d_in[5];
  const float* Wkv     = (const float*)d_in[6];
  const float* bkv     = (const float*)d_in[7];
  const float* Wo      = (const float*)d_in[8];
  const float* bo      = (const float*)d_in[9];
  float* out = (float*)d_out;
  (void)in_sizes; (void)n_in; (void)out_size;

  char* ws = (char*)d_ws;
  size_t off = 0;
  auto alloc = [&](size_t b) {
    void* p = ws + off;
    off = (off + b + 255) & ~(size_t)255;
    return p;
  };
  float*  lnp  = (float*)alloc((size_t)4 * 128 * 2 * sizeof(float));
  float*  muA  = (float*)alloc(4 * sizeof(float));
  float*  rsA  = (float*)alloc(4 * sizeof(float));
  __bf16* WqB  = (__bf16*)alloc((size_t)4096 * 512 * 2);
  __bf16* WkvB = (__bf16*)alloc((size_t)8192 * 512 * 2);
  __bf16* WoB  = (__bf16*)alloc((size_t)512 * 4096 * 2);
  __bf16* xnT  = (__bf16*)alloc((size_t)NB * SS * CC * 2);
  __bf16* ctxT = (__bf16*)alloc((size_t)NB * SS * CC * 2);

  const size_t PB = (size_t)SS * 4096 * 2;  // 16 MB per batch of q/k/v/y

  prep1<<<dim3(512 + 3 * 4096), dim3(256), 0, stream>>>(input, lnp, Wq, WqB, Wkv, WkvB, Wo, WoB);
  ln_final<<<dim3(4), dim3(128), 0, stream>>>(lnp, muA, rsA);
  transpose_nc<<<dim3(64, 16, 8), dim3(32, 8), 0, stream>>>(input, context, xnT, ctxT, muA, rsA,
                                                            gamma, beta);

  const size_t MiB = 1ull << 20;
  if (ws_size >= off + 16 * PB + 8 * MiB) {
    // Path A: full-batch buffers
    __bf16* qTb = (__bf16*)alloc(NB * PB);
    __bf16* kTb = (__bf16*)alloc(NB * PB);
    __bf16* vB  = (__bf16*)alloc(NB * PB);
    __bf16* yTb = (__bf16*)alloc(NB * PB);
    gemm_qkv<<<dim3(48, 8, 4), dim3(512), 0, stream>>>(WqB, WkvB, xnT, ctxT, bq, bkv, qTb, kTb,
                                                       vB);
    // 2-way qt split: keeps 512 blocks/dispatch (2 blocks/CU) while lowering
    // the per-dispatch max so rocprof top-5 reveals the next-biggest kernel.
    flash_attn<<<dim3(16, 8, 4), dim3(256), 0, stream>>>(qTb, kTb, vB, yTb, 0);
    flash_attn<<<dim3(16, 8, 4), dim3(256), 0, stream>>>(qTb, kTb, vB, yTb, 16);
    gemm_out_fused<<<dim3(4, 16, 4), dim3(512), 0, stream>>>(WoB, yTb, bo, input, out);
  } else if (ws_size >= off + 7 * PB + 8 * MiB) {
    // Path B: per-batch q/k/v, full yT
    __bf16* qTb = (__bf16*)alloc(PB);
    __bf16* kTb = (__bf16*)alloc(PB);
    __bf16* vB  = (__bf16*)alloc(PB);
    __bf16* yTb = (__bf16*)alloc(NB * PB);
    for (int n = 0; n < NB; ++n) {
      gemm_qkv<<<dim3(48, 8, 1), dim3(512), 0, stream>>>(WqB, WkvB, xnT + (size_t)n * SS * CC,
                                                         ctxT + (size_t)n * SS * CC, bq, bkv,
                                                         qTb, kTb, vB);
      flash_attn<<<dim3(32, 8, 1), dim3(256), 0, stream>>>(qTb, kTb, vB,
                                                           yTb + (size_t)n * SS * 4096, 0);
    }
    gemm_out_fused<<<dim3(4, 16, 4), dim3(512), 0, stream>>>(WoB, yTb, bo, input, out);
  } else {
    // Path C: everything per-batch
    __bf16* qTb = (__bf16*)alloc(PB);
    __bf16* kTb = (__bf16*)alloc(PB);
    __bf16* vB  = (__bf16*)alloc(PB);
    __bf16* yTb = (__bf16*)alloc(PB);
    for (int n = 0; n < NB; ++n) {
      gemm_qkv<<<dim3(48, 8, 1), dim3(512), 0, stream>>>(WqB, WkvB, xnT + (size_t)n * SS * CC,
                                                         ctxT + (size_t)n * SS * CC, bq, bkv,
                                                         qTb, kTb, vB);
      flash_attn<<<dim3(32, 8, 1), dim3(256), 0, stream>>>(qTb, kTb, vB, yTb, 0);
      gemm_out_fused<<<dim3(4, 16, 1), dim3(512), 0, stream>>>(WoB, yTb, bo,
                                                               input + (size_t)n * CC * SS,
                                                               out + (size_t)n * CC * SS);
    }
  }
}

// Round 4
// 887.284 us; speedup vs baseline: 1.2489x; 1.2489x over previous
//
#include <hip/hip_runtime.h>
#include <cstdint>
#include <cstddef>

// CrossAttention1d: N=4, C=512, S=2048, CTX=512, S2=2048, H=8
// R10: revert R9's flash split + setprio (graph ran halves concurrently;
// counters confounded; +48us regression). Add T13 defer-max to flash
// (per-wave skip of the 128-op O-rescale when tile max grows <= 8; LDS
// flag lets PV skip rescale per row-group). Fold ln_final into
// transpose_nc (one fewer dispatch). qkv (R7) / gemm_out (R8) unchanged.

#define NB 4
#define CC 512
#define SS 2048
#define HH 8
#define QK_SCALE 0.044194173824159216f  // 512^-0.5

typedef float  floatx4 __attribute__((ext_vector_type(4)));
typedef __bf16 bf16x8  __attribute__((ext_vector_type(8)));
typedef __bf16 bf16x4  __attribute__((ext_vector_type(4)));

__device__ __forceinline__ void async16(const void* g, void* l) {
  __builtin_amdgcn_global_load_lds((const __attribute__((address_space(1))) void*)g,
                                   (__attribute__((address_space(3))) void*)l, 16, 0, 0);
}

// DPP 16-lane row reductions (VALU pipe, not LDS). row_ror:n ctrl = 0x120+n.
template <int N>
__device__ __forceinline__ float dpp_ror_f(float v) {
  return __builtin_bit_cast(
      float, __builtin_amdgcn_update_dpp(0, __builtin_bit_cast(int, v), 0x120 + N, 0xf, 0xf, true));
}
__device__ __forceinline__ float red_max16(float v) {
  v = fmaxf(v, dpp_ror_f<8>(v));
  v = fmaxf(v, dpp_ror_f<4>(v));
  v = fmaxf(v, dpp_ror_f<2>(v));
  v = fmaxf(v, dpp_ror_f<1>(v));
  return v;
}
__device__ __forceinline__ float red_sum16(float v) {
  v += dpp_ror_f<8>(v);
  v += dpp_ror_f<4>(v);
  v += dpp_ror_f<2>(v);
  v += dpp_ror_f<1>(v);
  return v;
}

// ---------------- fused: LN partial stats (blocks 0..511) + weight casts ----------------
__global__ void prep1(const float* __restrict__ x, float* __restrict__ part,
                      const float* __restrict__ Wq, __bf16* __restrict__ WqB,
                      const float* __restrict__ Wkv, __bf16* __restrict__ WkvB,
                      const float* __restrict__ Wo, __bf16* __restrict__ WoB) {
  const int bx = blockIdx.x;
  if (bx < 512) {
    const int n = bx >> 7, cidx = bx & 127;
    const float* p = x + (size_t)n * (CC * SS) + (size_t)cidx * 8192;
    float s = 0.f, q = 0.f;
    for (int j = 0; j < 8; ++j) {
      floatx4 v = *(const floatx4*)&p[(j * 256 + threadIdx.x) * 4];
      for (int e = 0; e < 4; ++e) { s += v[e]; q += v[e] * v[e]; }
    }
    for (int off = 32; off >= 1; off >>= 1) {
      s += __shfl_down(s, off, 64);
      q += __shfl_down(q, off, 64);
    }
    __shared__ float shS[4], shQ[4];
    const int wave = threadIdx.x >> 6, lane = threadIdx.x & 63;
    if (lane == 0) { shS[wave] = s; shQ[wave] = q; }
    __syncthreads();
    if (threadIdx.x == 0) {
      part[bx * 2] = shS[0] + shS[1] + shS[2] + shS[3];
      part[bx * 2 + 1] = shQ[0] + shQ[1] + shQ[2] + shQ[3];
    }
  } else {
    const int r = bx - 512;
    const int y = r >> 12, xb = r & 4095;
    const float* s = y == 0 ? Wq : (y == 1 ? Wkv : Wo);
    __bf16* d = y == 0 ? WqB : (y == 1 ? WkvB : WoB);
    const int cnt = y == 1 ? 1048576 : 524288;
    int idx = xb * 256 + threadIdx.x;
    if (idx >= cnt) return;
    floatx4 v = ((const floatx4*)s)[idx];
    bf16x4 pk;
    for (int e = 0; e < 4; ++e) pk[e] = (__bf16)v[e];
    ((bf16x4*)d)[idx] = pk;
  }
}

// ---------------- fused LN-finalize + normalize+transpose (input) / transpose (context) ------
__global__ void transpose_nc(const float* __restrict__ input, const float* __restrict__ context,
                             __bf16* __restrict__ xnT, __bf16* __restrict__ ctxT,
                             const float* __restrict__ part,
                             const float* __restrict__ gamma, const float* __restrict__ beta) {
  __shared__ float t[32][33];
  __shared__ float red[4];
  const int n = blockIdx.z >> 1, which = blockIdx.z & 1;
  const int c0 = blockIdx.y * 32, s0 = blockIdx.x * 32;
  float muv = 0.f, rs = 1.f;
  if (!which) {
    // finalize LN stats in-block from the 128 partial pairs (L2-hot, tiny)
    const int tid = threadIdx.y * 32 + threadIdx.x;
    float s = 0.f, q = 0.f;
    if (tid < 128) { s = part[(n * 128 + tid) * 2]; q = part[(n * 128 + tid) * 2 + 1]; }
    for (int off = 32; off >= 1; off >>= 1) {
      s += __shfl_down(s, off, 64);
      q += __shfl_down(q, off, 64);
    }
    const int wv = tid >> 6, ln = tid & 63;
    if (wv < 2 && ln == 0) { red[wv * 2] = s; red[wv * 2 + 1] = q; }
    __syncthreads();
    float S = red[0] + red[2], Q = red[1] + red[3];
    const float inv = 1.f / (float)(CC * SS);
    float m = S * inv;
    float v = Q * inv - m * m;
    muv = m;
    rs = rsqrtf(v + 1e-5f);
  }
  const float* inp = (which ? context : input) + (size_t)n * CC * SS;
  __bf16* op = (which ? ctxT : xnT) + (size_t)n * SS * CC;
  for (int i = 0; i < 4; ++i) {
    int c = c0 + threadIdx.y + i * 8;
    float x = inp[(size_t)c * SS + s0 + threadIdx.x];
    if (!which) x = (x - muv) * rs * gamma[c] + beta[c];
    t[threadIdx.y + i * 8][threadIdx.x] = x;
  }
  __syncthreads();
  for (int i = 0; i < 4; ++i) {
    int s = s0 + threadIdx.y + i * 8;
    op[(size_t)s * CC + c0 + threadIdx.x] = (__bf16)t[threadIdx.x][threadIdx.y + i * 8];
  }
}

// ---------------- fused QKV GEMM: 256x256 tile, BK=64, 8 waves, deep pipeline ----------------
// A (row-major, lda=512): WqB (4096x512) or WkvB (8192x512).
// Bt (row-major, ldb=512): xnT or ctxT (s-major, 2048x512).
// C(256x256) per block; wave (wr,wc) owns 128(M) x 64(N).
__global__ void __launch_bounds__(512, 2) gemm_qkv(const __bf16* __restrict__ WqB,
                                                   const __bf16* __restrict__ WkvB,
                                                   const __bf16* __restrict__ xnT,
                                                   const __bf16* __restrict__ ctxT,
                                                   const float* __restrict__ bq,
                                                   const float* __restrict__ bkv,
                                                   __bf16* __restrict__ qT,
                                                   __bf16* __restrict__ kT,
                                                   __bf16* __restrict__ vv) {
  // LDS: A dbuf 2x(256x64) bf16 = 64KB, B dbuf = 64KB; epilogue transpose
  // buffer [256][264] bf16 = 135168B aliases the whole thing (max).
  __shared__ __align__(16) char smem[256 * 264 * 2];
  __bf16* lA = (__bf16*)smem;                  // [2][256*64]
  __bf16* lB = (__bf16*)(smem + 65536);        // [2][256*64]
  __bf16* lT = (__bf16*)smem;                  // [256][264]

  const int n = blockIdx.z, xb = blockIdx.x;
  const int n0 = blockIdx.y * 256;
  const bool isq = xb < 16;
  const int m0 = (isq ? xb : xb - 16) * 256;
  const __bf16* Aw = isq ? WqB : WkvB;
  const __bf16* Bt = (isq ? xnT : ctxT) + (size_t)n * SS * CC;
  const float* bias = isq ? bq : bkv;

  const int tid = threadIdx.x;
  const int wave = tid >> 6, lane = tid & 63;
  const int colv = lane & 15, g = lane >> 4;
  const int wr = wave >> 2, wc = wave & 3;   // 2(M) x 4(N) wave grid
  const int lrow = lane >> 3, lch = lane & 7;

  // stage K-tile t (64 channels) into buffer buf: 8 async16 per wave.
  auto stage = [&](int t, int buf) {
    const int k0 = t * 64;
    __bf16* dA = lA + buf * (256 * 64);
    __bf16* dB = lB + buf * (256 * 64);
#pragma unroll
    for (int j = 0; j < 4; ++j) {
      int r = wave * 32 + j * 8 + lrow;
      int ch = lch ^ (r & 7);
      async16(Aw + (size_t)(m0 + r) * 512 + k0 + ch * 8, dA + (wave * 32 + j * 8) * 64);
      async16(Bt + (size_t)(n0 + r) * 512 + k0 + ch * 8, dB + (wave * 32 + j * 8) * 64);
    }
  };

  floatx4 acc[8][4];
#pragma unroll
  for (int mf = 0; mf < 8; ++mf)
#pragma unroll
    for (int nf = 0; nf < 4; ++nf) acc[mf][nf] = (floatx4)0.f;

  // prologue: tiles 0,1 in flight; wait tile 0 landed (tile 1's 8 stay out).
  stage(0, 0);
  stage(1, 1);
  asm volatile("s_waitcnt vmcnt(8)" ::: "memory");
  __builtin_amdgcn_s_barrier();

  for (int t = 0; t < 8; ++t) {
    const int buf = t & 1;
    const __bf16* cA = lA + buf * (256 * 64);
    const __bf16* cB = lB + buf * (256 * 64);
#pragma unroll
    for (int c = 0; c < 2; ++c) {  // K-half (channels c*32..c*32+31)
      bf16x8 bfr[4], af[4];
      // phase A: B frags + A frags rows 0..63 of this wave's half
#pragma unroll
      for (int nf = 0; nf < 4; ++nf) {
        int rb = wc * 64 + nf * 16 + colv;
        bfr[nf] = *(const bf16x8*)&cB[rb * 64 + (((c * 4 + g) ^ (rb & 7)) << 3)];
      }
#pragma unroll
      for (int mf = 0; mf < 4; ++mf) {
        int ra = wr * 128 + mf * 16 + colv;
        af[mf] = *(const bf16x8*)&cA[ra * 64 + (((c * 4 + g) ^ (ra & 7)) << 3)];
      }
      __builtin_amdgcn_s_barrier();
      __builtin_amdgcn_s_setprio(1);
#pragma unroll
      for (int mf = 0; mf < 4; ++mf)
#pragma unroll
        for (int nf = 0; nf < 4; ++nf)
          acc[mf][nf] =
              __builtin_amdgcn_mfma_f32_16x16x32_bf16(af[mf], bfr[nf], acc[mf][nf], 0, 0, 0);
      __builtin_amdgcn_s_setprio(0);
      __builtin_amdgcn_s_barrier();
      // phase B: A frags rows 64..127 of this wave's half
#pragma unroll
      for (int mf = 0; mf < 4; ++mf) {
        int ra = wr * 128 + 64 + mf * 16 + colv;
        af[mf] = *(const bf16x8*)&cA[ra * 64 + (((c * 4 + g) ^ (ra & 7)) << 3)];
      }
      __builtin_amdgcn_s_barrier();
      __builtin_amdgcn_s_setprio(1);
#pragma unroll
      for (int mf = 0; mf < 4; ++mf)
#pragma unroll
        for (int nf = 0; nf < 4; ++nf)
          acc[mf + 4][nf] =
              __builtin_amdgcn_mfma_f32_16x16x32_bf16(af[mf], bfr[nf], acc[mf + 4][nf], 0, 0, 0);
      __builtin_amdgcn_s_setprio(0);
      __builtin_amdgcn_s_barrier();
    }
    // tile boundary: all waves past trailing barrier => buf's reads retired.
    if (t < 6) {
      stage(t + 2, buf);
      asm volatile("s_waitcnt vmcnt(8)" ::: "memory");  // tile t+1 landed
    } else {
      asm volatile("s_waitcnt vmcnt(0)" ::: "memory");
    }
    __builtin_amdgcn_s_barrier();
  }

  // ---------------- epilogue ----------------
  if (isq || m0 < 4096) {
    // Q / K: transposed store dst[(n0+nl)*4096 + m0+ml] via LDS [256][264]
    __bf16* dst = (isq ? qT : kT) + (size_t)n * SS * 4096;
#pragma unroll
    for (int mf = 0; mf < 8; ++mf) {
      int mb = wr * 128 + mf * 16 + g * 4;
      floatx4 bv = *(const floatx4*)&bias[m0 + mb];
#pragma unroll
      for (int nf = 0; nf < 4; ++nf) {
        int nl = wc * 64 + nf * 16 + colv;
        bf16x4 pk;
#pragma unroll
        for (int i = 0; i < 4; ++i) pk[i] = (__bf16)(acc[mf][nf][i] + bv[i]);
        *(bf16x4*)&lT[nl * 264 + mb] = pk;
      }
    }
    asm volatile("s_waitcnt lgkmcnt(0)" ::: "memory");  // ds_writes visible
    __builtin_amdgcn_s_barrier();
#pragma unroll
    for (int p = 0; p < 16; ++p) {
      int row = p * 16 + (tid >> 5);
      int ch = tid & 31;
      bf16x8 v = *(const bf16x8*)&lT[row * 264 + ch * 8];
      *(bf16x8*)&dst[(size_t)(n0 + row) * 4096 + m0 + ch * 8] = v;
    }
  } else {
    // V: channel-major direct store vn[o*SS + s]
    __bf16* vn = vv + (size_t)n * 4096 * SS;
#pragma unroll
    for (int mf = 0; mf < 8; ++mf) {
      int mb = wr * 128 + mf * 16 + g * 4;
      int o = m0 + mb - 4096;
      floatx4 bv = *(const floatx4*)&bias[m0 + mb];
#pragma unroll
      for (int nf = 0; nf < 4; ++nf) {
        int s = n0 + wc * 64 + nf * 16 + colv;
#pragma unroll
        for (int i = 0; i < 4; ++i)
          vn[(size_t)(o + i) * SS + s] = (__bf16)(acc[mf][nf][i] + bv[i]);
      }
    }
  }
}

// ---------------- flash attention (PV d-split, DPP softmax, T13 defer-max) ----------------
__global__ void __launch_bounds__(256) flash_attn(const __bf16* __restrict__ qT,
                                                  const __bf16* __restrict__ kT,
                                                  const __bf16* __restrict__ vv,
                                                  __bf16* __restrict__ yT) {
  const int n = blockIdx.z, h = blockIdx.y, qt = blockIdx.x;
  const int tid = threadIdx.x;
  const int wave = tid >> 6, lane = tid & 63;
  const int colv = lane & 15, g = lane >> 4;

  const __bf16* qTn = qT + (size_t)n * SS * 4096;
  const __bf16* kTn = kT + (size_t)n * SS * 4096;
  const __bf16* vn  = vv + (size_t)n * 4096 * SS;
  __bf16* yTn = yT + (size_t)n * SS * 4096;

  const int qrow0 = qt * 64 + wave * 16;

  __shared__ __bf16 kbuf[32 * 512];
  __shared__ __bf16 vbuf[512 * 32];
  __shared__ __bf16 pbuf[4 * 16 * 88];
  __shared__ float axs[64];
  __shared__ float ils[64];
  __shared__ int sfl[4];  // per-wave "skipped rescale" flag (T13)

  bf16x8 qf[16];
  {
    const __bf16* qp = qTn + (size_t)(qrow0 + colv) * 4096 + h * 512 + g * 8;
#pragma unroll
    for (int kc = 0; kc < 16; ++kc) qf[kc] = *(const bf16x8*)(qp + kc * 32);
  }

  floatx4 Oacc[32];
#pragma unroll
  for (int t = 0; t < 32; ++t) Oacc[t] = (floatx4)0.f;
  float mrun[4] = {-1e30f, -1e30f, -1e30f, -1e30f};
  float lrun[4] = {0.f, 0.f, 0.f, 0.f};

  __bf16* pb = pbuf + wave * (16 * 88);

  auto stageK = [&](int kt) {
    const int key0 = kt * 32;
#pragma unroll
    for (int j = 0; j < 8; ++j) {
      int row = wave * 8 + j;
      const __bf16* src = kTn + (size_t)(key0 + row) * 4096 + h * 512 + ((lane ^ (row & 7)) << 3);
      async16(src, &kbuf[row * 512]);
    }
  };
  auto stageV = [&](int kt) {
    const int key0 = kt * 32;
#pragma unroll
    for (int j = 0; j < 8; ++j) {
      int i = wave * 8 + j;
      int row = i * 16 + (lane >> 2);
      int ch = (lane & 3) ^ (row & 3);
      const __bf16* src = vn + (size_t)(h * 512 + row) * SS + key0 + ch * 8;
      async16(src, &vbuf[i * 16 * 32]);
    }
  };

  stageK(0);
  stageV(0);

  for (int kt = 0; kt < 64; ++kt) {
    __syncthreads();  // staged K/V drained & visible

    floatx4 sc[2];
    sc[0] = (floatx4)0.f;
    sc[1] = (floatx4)0.f;
#pragma unroll
    for (int ct = 0; ct < 2; ++ct) {
      int key = ct * 16 + colv;
      const __bf16* kb = &kbuf[key * 512];
      int sw = key & 7;
#pragma unroll
      for (int kc = 0; kc < 16; ++kc) {
        bf16x8 bfr = *(const bf16x8*)(kb + (((kc * 4 + g) ^ sw) << 3));
        sc[ct] = __builtin_amdgcn_mfma_f32_16x16x32_bf16(qf[kc], bfr, sc[ct], 0, 0, 0);
      }
    }

    // T13 defer-max: skip rescale while the tile max grows <= THR=8.
    float p[2][4];
    float mx[4];
    float needs = -1e30f;
#pragma unroll
    for (int i = 0; i < 4; ++i) {
      mx[i] = red_max16(fmaxf(sc[0][i], sc[1][i])) * QK_SCALE;
      needs = fmaxf(needs, mx[i] - mrun[i]);
    }
    const bool skip = __all(needs <= 8.0f);  // wave-uniform
    if (skip) {
#pragma unroll
      for (int i = 0; i < 4; ++i) {
        float rs = 0.f;
#pragma unroll
        for (int ct = 0; ct < 2; ++ct) {
          float pvv = __expf(sc[ct][i] * QK_SCALE - mrun[i]);
          p[ct][i] = pvv;
          rs += pvv;
        }
        lrun[i] += red_sum16(rs);
      }
      if (lane == 0) sfl[wave] = 1;
    } else {
      float alpha[4];
#pragma unroll
      for (int i = 0; i < 4; ++i) {
        float mnew = fmaxf(mrun[i], mx[i]);
        alpha[i] = __expf(mrun[i] - mnew);
        float rs = 0.f;
#pragma unroll
        for (int ct = 0; ct < 2; ++ct) {
          float pvv = __expf(sc[ct][i] * QK_SCALE - mnew);
          p[ct][i] = pvv;
          rs += pvv;
        }
        lrun[i] = lrun[i] * alpha[i] + red_sum16(rs);
        mrun[i] = mnew;
      }
      if (colv == 0) {
        floatx4 av;
#pragma unroll
        for (int i = 0; i < 4; ++i) av[i] = alpha[i];
        *(floatx4*)&axs[wave * 16 + g * 4] = av;
      }
      if (lane == 0) sfl[wave] = 0;
    }
#pragma unroll
    for (int ct = 0; ct < 2; ++ct)
#pragma unroll
      for (int i = 0; i < 4; ++i)
        pb[(g * 4 + i) * 88 + ct * 16 + colv] = (__bf16)p[ct][i];
    __syncthreads();  // P + alpha + flags ready; kbuf reads done

    if (kt < 63) stageK(kt + 1);  // kbuf free during PV

#pragma unroll
    for (int qt4 = 0; qt4 < 4; ++qt4) {
      if (sfl[qt4]) continue;  // owner wave deferred: alpha == 1
      floatx4 av = *(const floatx4*)&axs[qt4 * 16 + g * 4];
#pragma unroll
      for (int dt = 0; dt < 8; ++dt) {
        floatx4 o = Oacc[qt4 * 8 + dt];
#pragma unroll
        for (int i = 0; i < 4; ++i) o[i] *= av[i];
        Oacc[qt4 * 8 + dt] = o;
      }
    }
    bf16x8 pa[4];
#pragma unroll
    for (int qt4 = 0; qt4 < 4; ++qt4)
      pa[qt4] = *(const bf16x8*)&pbuf[qt4 * (16 * 88) + colv * 88 + g * 8];
#pragma unroll
    for (int dt = 0; dt < 8; ++dt) {
      int drow = wave * 128 + dt * 16 + colv;
      bf16x8 vb = *(const bf16x8*)&vbuf[drow * 32 + ((g ^ (drow & 3)) << 3)];
#pragma unroll
      for (int qt4 = 0; qt4 < 4; ++qt4)
        Oacc[qt4 * 8 + dt] = __builtin_amdgcn_mfma_f32_16x16x32_bf16(pa[qt4], vb,
                                                                    Oacc[qt4 * 8 + dt], 0, 0, 0);
    }
    __syncthreads();  // PV reads done -> vbuf free
    if (kt < 63) stageV(kt + 1);
  }

  if (colv == 0) {
    floatx4 lv;
#pragma unroll
    for (int i = 0; i < 4; ++i) lv[i] = 1.f / lrun[i];
    *(floatx4*)&ils[wave * 16 + g * 4] = lv;
  }
  __syncthreads();
#pragma unroll
  for (int qt4 = 0; qt4 < 4; ++qt4) {
    floatx4 lv = *(const floatx4*)&ils[qt4 * 16 + g * 4];
#pragma unroll
    for (int dt = 0; dt < 8; ++dt)
#pragma unroll
      for (int i = 0; i < 4; ++i) {
        size_t idx = (size_t)(qt * 64 + qt4 * 16 + g * 4 + i) * 4096 + h * 512 + wave * 128 +
                     dt * 16 + colv;
        yTn[idx] = (__bf16)(Oacc[qt4 * 8 + dt][i] * lv[i]);
      }
  }
}

// ---------------- fused out GEMM: out[c][s] = input + bo[c] + Wo·y ----------------
// A = WoB (M=512=c rows, K=4096), Bt = yT (N=2048=s rows, K=4096).
// 128(c) x 128(s) tile, grid (4,16,4)=256 blocks (1/CU), 512 threads
// (8 waves 2x4, each 64x32), BK=64, triple-buffered LDS (96KB), counted
// vmcnt at boundaries, stores s-contiguous fp32 with residual+bias epilogue.
__global__ void __launch_bounds__(512) gemm_out_fused(const __bf16* __restrict__ Wo,
                                                      const __bf16* __restrict__ yT,
                                                      const float* __restrict__ bo,
                                                      const float* __restrict__ input,
                                                      float* __restrict__ out) {
  __shared__ __bf16 lA[3][128 * 64], lB[3][128 * 64];  // 96 KB
  const int n = blockIdx.z;
  const int m0 = blockIdx.x * 128, n0 = blockIdx.y * 128;
  const __bf16* Bt = yT + (size_t)n * SS * 4096;
  const int tid = threadIdx.x;
  const int wave = tid >> 6, lane = tid & 63;
  const int colv = lane & 15, g = lane >> 4;
  const int wr = wave >> 2, wc = wave & 3;   // 2(M) x 4(N); wave-tile 64x32
  const int lrow = lane >> 3, lch = lane & 7;

  // stage K-tile t: per wave 2 async16 for A + 2 for B (4 vmcnt ticks).
  auto stage = [&](int t, int buf) {
    const int k0 = t * 64;
#pragma unroll
    for (int j = 0; j < 2; ++j) {
      int r = wave * 16 + j * 8 + lrow;
      int ch = lch ^ (r & 7);
      async16(Wo + (size_t)(m0 + r) * 4096 + k0 + ch * 8, &lA[buf][(wave * 16 + j * 8) * 64]);
      async16(Bt + (size_t)(n0 + r) * 4096 + k0 + ch * 8, &lB[buf][(wave * 16 + j * 8) * 64]);
    }
  };

  floatx4 acc[4][2];
#pragma unroll
  for (int mt = 0; mt < 4; ++mt)
#pragma unroll
    for (int nt = 0; nt < 2; ++nt) acc[mt][nt] = (floatx4)0.f;

  // prologue: 3 tiles in flight; wait tile 0 landed (8 newer stay out).
  stage(0, 0);
  stage(1, 1);
  stage(2, 2);
  asm volatile("s_waitcnt vmcnt(8)" ::: "memory");
  __builtin_amdgcn_s_barrier();

  int buf = 0;
  for (int t = 0; t < 64; ++t) {
#pragma unroll
    for (int c = 0; c < 2; ++c) {  // K-half (channels c*32..c*32+31)
      bf16x8 af[4], bf[2];
#pragma unroll
      for (int mt = 0; mt < 4; ++mt) {
        int ra = wr * 64 + mt * 16 + colv;
        af[mt] = *(const bf16x8*)&lA[buf][ra * 64 + (((c * 4 + g) ^ (ra & 7)) << 3)];
      }
#pragma unroll
      for (int nt = 0; nt < 2; ++nt) {
        int rb = wc * 32 + nt * 16 + colv;
        bf[nt] = *(const bf16x8*)&lB[buf][rb * 64 + (((c * 4 + g) ^ (rb & 7)) << 3)];
      }
#pragma unroll
      for (int mt = 0; mt < 4; ++mt)
#pragma unroll
        for (int nt = 0; nt < 2; ++nt)
          acc[mt][nt] =
              __builtin_amdgcn_mfma_f32_16x16x32_bf16(af[mt], bf[nt], acc[mt][nt], 0, 0, 0);
    }
    if (t == 63) break;
    __builtin_amdgcn_s_barrier();  // all reads of buf retired
    if (t < 61) {
      stage(t + 3, buf);           // refill freed buf
      asm volatile("s_waitcnt vmcnt(8)" ::: "memory");  // tile t+1 landed
    } else if (t == 61) {
      asm volatile("s_waitcnt vmcnt(4)" ::: "memory");
    } else {  // t == 62
      asm volatile("s_waitcnt vmcnt(0)" ::: "memory");
    }
    __builtin_amdgcn_s_barrier();  // everyone's t+1 landed
    buf = (buf == 2) ? 0 : buf + 1;
  }

  // epilogue: c = m0+wr*64+mt*16+g*4+i ; s = n0+wc*32+nt*16+colv ; fp32 direct
#pragma unroll
  for (int mt = 0; mt < 4; ++mt) {
#pragma unroll
    for (int i = 0; i < 4; ++i) {
      int c = m0 + wr * 64 + mt * 16 + g * 4 + i;
      float bov = bo[c];
      size_t rowb = ((size_t)n * CC + c) * SS;
#pragma unroll
      for (int nt = 0; nt < 2; ++nt) {
        int s = n0 + wc * 32 + nt * 16 + colv;
        out[rowb + s] = acc[mt][nt][i] + bov + input[rowb + s];
      }
    }
  }
}

// ---------------- host launcher ----------------
extern "C" void kernel_launch(void* const* d_in, const int* in_sizes, int n_in,
                              void* d_out, int out_size, void* d_ws, size_t ws_size,
                              hipStream_t stream) {
  const float* input   = (const float*)d_in[0];
  const float* context = (const float*)d_in[1];
  const float* gamma   = (const float*)d_in[2];
  const float* beta    = (const float*)d_in[3];
  const float* Wq      = (const float*)d_in[4];
  const float* bq      = (const float*)d_in[5];
  const float* Wkv     = (const float*)d_in[6];
  const float* bkv     = (const float*)d_in[7];
  const float* Wo      = (const float*)d_in[8];
  const float* bo      = (const float*)d_in[9];
  float* out = (float*)d_out;
  (void)in_sizes; (void)n_in; (void)out_size;

  char* ws = (char*)d_ws;
  size_t off = 0;
  auto alloc = [&](size_t b) {
    void* p = ws + off;
    off = (off + b + 255) & ~(size_t)255;
    return p;
  };
  float*  lnp  = (float*)alloc((size_t)4 * 128 * 2 * sizeof(float));
  __bf16* WqB  = (__bf16*)alloc((size_t)4096 * 512 * 2);
  __bf16* WkvB = (__bf16*)alloc((size_t)8192 * 512 * 2);
  __bf16* WoB  = (__bf16*)alloc((size_t)512 * 4096 * 2);
  __bf16* xnT  = (__bf16*)alloc((size_t)NB * SS * CC * 2);
  __bf16* ctxT = (__bf16*)alloc((size_t)NB * SS * CC * 2);

  const size_t PB = (size_t)SS * 4096 * 2;  // 16 MB per batch of q/k/v/y

  prep1<<<dim3(512 + 3 * 4096), dim3(256), 0, stream>>>(input, lnp, Wq, WqB, Wkv, WkvB, Wo, WoB);
  transpose_nc<<<dim3(64, 16, 8), dim3(32, 8), 0, stream>>>(input, context, xnT, ctxT, lnp,
                                                            gamma, beta);

  const size_t MiB = 1ull << 20;
  if (ws_size >= off + 16 * PB + 8 * MiB) {
    // Path A: full-batch buffers
    __bf16* qTb = (__bf16*)alloc(NB * PB);
    __bf16* kTb = (__bf16*)alloc(NB * PB);
    __bf16* vB  = (__bf16*)alloc(NB * PB);
    __bf16* yTb = (__bf16*)alloc(NB * PB);
    gemm_qkv<<<dim3(48, 8, 4), dim3(512), 0, stream>>>(WqB, WkvB, xnT, ctxT, bq, bkv, qTb, kTb,
                                                       vB);
    flash_attn<<<dim3(32, 8, 4), dim3(256), 0, stream>>>(qTb, kTb, vB, yTb);
    gemm_out_fused<<<dim3(4, 16, 4), dim3(512), 0, stream>>>(WoB, yTb, bo, input, out);
  } else if (ws_size >= off + 7 * PB + 8 * MiB) {
    // Path B: per-batch q/k/v, full yT
    __bf16* qTb = (__bf16*)alloc(PB);
    __bf16* kTb = (__bf16*)alloc(PB);
    __bf16* vB  = (__bf16*)alloc(PB);
    __bf16* yTb = (__bf16*)alloc(NB * PB);
    for (int n = 0; n < NB; ++n) {
      gemm_qkv<<<dim3(48, 8, 1), dim3(512), 0, stream>>>(WqB, WkvB, xnT + (size_t)n * SS * CC,
                                                         ctxT + (size_t)n * SS * CC, bq, bkv,
                                                         qTb, kTb, vB);
      flash_attn<<<dim3(32, 8, 1), dim3(256), 0, stream>>>(qTb, kTb, vB,
                                                           yTb + (size_t)n * SS * 4096);
    }
    gemm_out_fused<<<dim3(4, 16, 4), dim3(512), 0, stream>>>(WoB, yTb, bo, input, out);
  } else {
    // Path C: everything per-batch
    __bf16* qTb = (__bf16*)alloc(PB);
    __bf16* kTb = (__bf16*)alloc(PB);
    __bf16* vB  = (__bf16*)alloc(PB);
    __bf16* yTb = (__bf16*)alloc(PB);
    for (int n = 0; n < NB; ++n) {
      gemm_qkv<<<dim3(48, 8, 1), dim3(512), 0, stream>>>(WqB, WkvB, xnT + (size_t)n * SS * CC,
                                                         ctxT + (size_t)n * SS * CC, bq, bkv,
                                                         qTb, kTb, vB);
      flash_attn<<<dim3(32, 8, 1), dim3(256), 0, stream>>>(qTb, kTb, vB, yTb);
      gemm_out_fused<<<dim3(4, 16, 1), dim3(512), 0, stream>>>(WoB, yTb, bo,
                                                               input + (size_t)n * CC * SS,
                                                               out + (size_t)n * CC * SS);
    }
  }
}

// Round 5
// 845.303 us; speedup vs baseline: 1.3109x; 1.0497x over previous
//
#include <hip/hip_runtime.h>
#include <cstdint>
#include <cstddef>

// CrossAttention1d: N=4, C=512, S=2048, CTX=512, S2=2048, H=8
// R11: occupancy round. Cross-session clock confound identified (hbm_gbps
// 815->1043 for identical flash bytes): judge by dur/flash ratio. Both
// non-flash GEMMs were 1 block/CU (LDS 135KB / 96KB+256-block grid) ->
// latency-bound, clock-invariant stalls. qkv: 128^2 tile, 4 waves, BK=64,
// dbuf 64KB -> 2 blocks/CU. out: 128x64 tile, 4 waves, dbuf 48KB, 512
// blocks -> 2/CU. Same counted-vmcnt loop template (R8), epilogue math
// unchanged. flash (T13) / prep1 / transpose_nc unchanged.

#define NB 4
#define CC 512
#define SS 2048
#define HH 8
#define QK_SCALE 0.044194173824159216f  // 512^-0.5

typedef float  floatx4 __attribute__((ext_vector_type(4)));
typedef __bf16 bf16x8  __attribute__((ext_vector_type(8)));
typedef __bf16 bf16x4  __attribute__((ext_vector_type(4)));

__device__ __forceinline__ void async16(const void* g, void* l) {
  __builtin_amdgcn_global_load_lds((const __attribute__((address_space(1))) void*)g,
                                   (__attribute__((address_space(3))) void*)l, 16, 0, 0);
}

// DPP 16-lane row reductions (VALU pipe, not LDS). row_ror:n ctrl = 0x120+n.
template <int N>
__device__ __forceinline__ float dpp_ror_f(float v) {
  return __builtin_bit_cast(
      float, __builtin_amdgcn_update_dpp(0, __builtin_bit_cast(int, v), 0x120 + N, 0xf, 0xf, true));
}
__device__ __forceinline__ float red_max16(float v) {
  v = fmaxf(v, dpp_ror_f<8>(v));
  v = fmaxf(v, dpp_ror_f<4>(v));
  v = fmaxf(v, dpp_ror_f<2>(v));
  v = fmaxf(v, dpp_ror_f<1>(v));
  return v;
}
__device__ __forceinline__ float red_sum16(float v) {
  v += dpp_ror_f<8>(v);
  v += dpp_ror_f<4>(v);
  v += dpp_ror_f<2>(v);
  v += dpp_ror_f<1>(v);
  return v;
}

// ---------------- fused: LN partial stats (blocks 0..511) + weight casts ----------------
__global__ void prep1(const float* __restrict__ x, float* __restrict__ part,
                      const float* __restrict__ Wq, __bf16* __restrict__ WqB,
                      const float* __restrict__ Wkv, __bf16* __restrict__ WkvB,
                      const float* __restrict__ Wo, __bf16* __restrict__ WoB) {
  const int bx = blockIdx.x;
  if (bx < 512) {
    const int n = bx >> 7, cidx = bx & 127;
    const float* p = x + (size_t)n * (CC * SS) + (size_t)cidx * 8192;
    float s = 0.f, q = 0.f;
    for (int j = 0; j < 8; ++j) {
      floatx4 v = *(const floatx4*)&p[(j * 256 + threadIdx.x) * 4];
      for (int e = 0; e < 4; ++e) { s += v[e]; q += v[e] * v[e]; }
    }
    for (int off = 32; off >= 1; off >>= 1) {
      s += __shfl_down(s, off, 64);
      q += __shfl_down(q, off, 64);
    }
    __shared__ float shS[4], shQ[4];
    const int wave = threadIdx.x >> 6, lane = threadIdx.x & 63;
    if (lane == 0) { shS[wave] = s; shQ[wave] = q; }
    __syncthreads();
    if (threadIdx.x == 0) {
      part[bx * 2] = shS[0] + shS[1] + shS[2] + shS[3];
      part[bx * 2 + 1] = shQ[0] + shQ[1] + shQ[2] + shQ[3];
    }
  } else {
    const int r = bx - 512;
    const int y = r >> 12, xb = r & 4095;
    const float* s = y == 0 ? Wq : (y == 1 ? Wkv : Wo);
    __bf16* d = y == 0 ? WqB : (y == 1 ? WkvB : WoB);
    const int cnt = y == 1 ? 1048576 : 524288;
    int idx = xb * 256 + threadIdx.x;
    if (idx >= cnt) return;
    floatx4 v = ((const floatx4*)s)[idx];
    bf16x4 pk;
    for (int e = 0; e < 4; ++e) pk[e] = (__bf16)v[e];
    ((bf16x4*)d)[idx] = pk;
  }
}

// ---------------- fused LN-finalize + normalize+transpose (input) / transpose (context) ------
__global__ void transpose_nc(const float* __restrict__ input, const float* __restrict__ context,
                             __bf16* __restrict__ xnT, __bf16* __restrict__ ctxT,
                             const float* __restrict__ part,
                             const float* __restrict__ gamma, const float* __restrict__ beta) {
  __shared__ float t[32][33];
  __shared__ float red[4];
  const int n = blockIdx.z >> 1, which = blockIdx.z & 1;
  const int c0 = blockIdx.y * 32, s0 = blockIdx.x * 32;
  float muv = 0.f, rs = 1.f;
  if (!which) {
    // finalize LN stats in-block from the 128 partial pairs (L2-hot, tiny)
    const int tid = threadIdx.y * 32 + threadIdx.x;
    float s = 0.f, q = 0.f;
    if (tid < 128) { s = part[(n * 128 + tid) * 2]; q = part[(n * 128 + tid) * 2 + 1]; }
    for (int off = 32; off >= 1; off >>= 1) {
      s += __shfl_down(s, off, 64);
      q += __shfl_down(q, off, 64);
    }
    const int wv = tid >> 6, ln = tid & 63;
    if (wv < 2 && ln == 0) { red[wv * 2] = s; red[wv * 2 + 1] = q; }
    __syncthreads();
    float S = red[0] + red[2], Q = red[1] + red[3];
    const float inv = 1.f / (float)(CC * SS);
    float m = S * inv;
    float v = Q * inv - m * m;
    muv = m;
    rs = rsqrtf(v + 1e-5f);
  }
  const float* inp = (which ? context : input) + (size_t)n * CC * SS;
  __bf16* op = (which ? ctxT : xnT) + (size_t)n * SS * CC;
  for (int i = 0; i < 4; ++i) {
    int c = c0 + threadIdx.y + i * 8;
    float x = inp[(size_t)c * SS + s0 + threadIdx.x];
    if (!which) x = (x - muv) * rs * gamma[c] + beta[c];
    t[threadIdx.y + i * 8][threadIdx.x] = x;
  }
  __syncthreads();
  for (int i = 0; i < 4; ++i) {
    int s = s0 + threadIdx.y + i * 8;
    op[(size_t)s * CC + c0 + threadIdx.x] = (__bf16)t[threadIdx.x][threadIdx.y + i * 8];
  }
}

// ---------------- fused QKV GEMM: 128x128 tile, BK=64, 4 waves, dbuf 64KB ----------------
// A (row-major, lda=512): WqB (4096x512) or WkvB (8192x512).
// Bt (row-major, ldb=512): xnT or ctxT (s-major, 2048x512).
// C(128x128) per block; wave (wm,wn) owns 64x64; 2 blocks/CU resident.
__global__ void __launch_bounds__(256) gemm_qkv(const __bf16* __restrict__ WqB,
                                                const __bf16* __restrict__ WkvB,
                                                const __bf16* __restrict__ xnT,
                                                const __bf16* __restrict__ ctxT,
                                                const float* __restrict__ bq,
                                                const float* __restrict__ bkv,
                                                __bf16* __restrict__ qT,
                                                __bf16* __restrict__ kT,
                                                __bf16* __restrict__ vv) {
  // LDS: A dbuf 2x(128x64) = 32KB + B dbuf 32KB = 64KB; epilogue transpose
  // buffer [128][136] bf16 = 34816B aliases the same region.
  __shared__ __align__(16) char smem[65536];
  __bf16* lA = (__bf16*)smem;               // [2][128*64]
  __bf16* lB = (__bf16*)(smem + 32768);     // [2][128*64]
  __bf16* lT = (__bf16*)smem;               // [128][136]

  const int n = blockIdx.z, xb = blockIdx.x;
  const int n0 = blockIdx.y * 128;
  const bool isq = xb < 32;
  const int m0 = (isq ? xb : xb - 32) * 128;
  const __bf16* Aw = isq ? WqB : WkvB;
  const __bf16* Bt = (isq ? xnT : ctxT) + (size_t)n * SS * CC;
  const float* bias = isq ? bq : bkv;

  const int tid = threadIdx.x;
  const int wave = tid >> 6, lane = tid & 63;
  const int colv = lane & 15, g = lane >> 4;
  const int wm = wave & 1, wn = wave >> 1;   // 2(M) x 2(N) wave grid, 64x64 each
  const int lrow = lane >> 3, lch = lane & 7;

  // stage K-tile t into buffer buf: 4 A + 4 B async16 per wave (8 ticks).
  auto stage = [&](int t, int buf) {
    const int k0 = t * 64;
    __bf16* dA = lA + buf * (128 * 64);
    __bf16* dB = lB + buf * (128 * 64);
#pragma unroll
    for (int j = 0; j < 4; ++j) {
      int r = wave * 32 + j * 8 + lrow;
      int ch = lch ^ (r & 7);
      async16(Aw + (size_t)(m0 + r) * 512 + k0 + ch * 8, dA + (wave * 32 + j * 8) * 64);
      async16(Bt + (size_t)(n0 + r) * 512 + k0 + ch * 8, dB + (wave * 32 + j * 8) * 64);
    }
  };

  floatx4 acc[4][4];
#pragma unroll
  for (int mt = 0; mt < 4; ++mt)
#pragma unroll
    for (int nt = 0; nt < 4; ++nt) acc[mt][nt] = (floatx4)0.f;

  // prologue: tiles 0,1 in flight; wait tile 0 landed (tile 1's 8 stay out).
  stage(0, 0);
  stage(1, 1);
  asm volatile("s_waitcnt vmcnt(8)" ::: "memory");
  __builtin_amdgcn_s_barrier();

  for (int t = 0; t < 8; ++t) {
    const __bf16* cA = lA + (t & 1) * (128 * 64);
    const __bf16* cB = lB + (t & 1) * (128 * 64);
#pragma unroll
    for (int c = 0; c < 2; ++c) {  // K-half (channels c*32..c*32+31)
      bf16x8 af[4], bfr[4];
#pragma unroll
      for (int mt = 0; mt < 4; ++mt) {
        int ra = wm * 64 + mt * 16 + colv;
        af[mt] = *(const bf16x8*)&cA[ra * 64 + (((c * 4 + g) ^ (ra & 7)) << 3)];
      }
#pragma unroll
      for (int nt = 0; nt < 4; ++nt) {
        int rb = wn * 64 + nt * 16 + colv;
        bfr[nt] = *(const bf16x8*)&cB[rb * 64 + (((c * 4 + g) ^ (rb & 7)) << 3)];
      }
#pragma unroll
      for (int mt = 0; mt < 4; ++mt)
#pragma unroll
        for (int nt = 0; nt < 4; ++nt)
          acc[mt][nt] =
              __builtin_amdgcn_mfma_f32_16x16x32_bf16(af[mt], bfr[nt], acc[mt][nt], 0, 0, 0);
    }
    if (t == 7) break;
    __builtin_amdgcn_s_barrier();  // all reads of this buf retired
    if (t < 6) {
      stage(t + 2, t & 1);         // refill freed buf
      asm volatile("s_waitcnt vmcnt(8)" ::: "memory");  // tile t+1 landed
    } else {
      asm volatile("s_waitcnt vmcnt(0)" ::: "memory");
    }
    __builtin_amdgcn_s_barrier();  // everyone's t+1 landed
  }

  // ---------------- epilogue ----------------
  if (isq || m0 < 4096) {
    // Q / K: transposed store dst[(n0+nl)*4096 + m0+ml] via LDS [128][136]
    __bf16* dst = (isq ? qT : kT) + (size_t)n * SS * 4096;
    __syncthreads();  // mainloop LDS reads done -> lT alias safe
#pragma unroll
    for (int mt = 0; mt < 4; ++mt) {
      int mb = wm * 64 + mt * 16 + g * 4;
      floatx4 bv = *(const floatx4*)&bias[m0 + mb];
#pragma unroll
      for (int nt = 0; nt < 4; ++nt) {
        int nl = wn * 64 + nt * 16 + colv;
        bf16x4 pk;
#pragma unroll
        for (int i = 0; i < 4; ++i) pk[i] = (__bf16)(acc[mt][nt][i] + bv[i]);
        *(bf16x4*)&lT[nl * 136 + mb] = pk;
      }
    }
    __syncthreads();  // ds_writes visible
#pragma unroll
    for (int p = 0; p < 8; ++p) {
      int row = p * 16 + (tid >> 4);
      int ch = tid & 15;
      bf16x8 v = *(const bf16x8*)&lT[row * 136 + ch * 8];
      *(bf16x8*)&dst[(size_t)(n0 + row) * 4096 + m0 + ch * 8] = v;
    }
  } else {
    // V: channel-major direct store vn[o*SS + s]
    __bf16* vn = vv + (size_t)n * 4096 * SS;
#pragma unroll
    for (int mt = 0; mt < 4; ++mt) {
      int mb = wm * 64 + mt * 16 + g * 4;
      int o = m0 + mb - 4096;
      floatx4 bv = *(const floatx4*)&bias[m0 + mb];
#pragma unroll
      for (int nt = 0; nt < 4; ++nt) {
        int s = n0 + wn * 64 + nt * 16 + colv;
#pragma unroll
        for (int i = 0; i < 4; ++i)
          vn[(size_t)(o + i) * SS + s] = (__bf16)(acc[mt][nt][i] + bv[i]);
      }
    }
  }
}

// ---------------- flash attention (PV d-split, DPP softmax, T13 defer-max) ----------------
__global__ void __launch_bounds__(256) flash_attn(const __bf16* __restrict__ qT,
                                                  const __bf16* __restrict__ kT,
                                                  const __bf16* __restrict__ vv,
                                                  __bf16* __restrict__ yT) {
  const int n = blockIdx.z, h = blockIdx.y, qt = blockIdx.x;
  const int tid = threadIdx.x;
  const int wave = tid >> 6, lane = tid & 63;
  const int colv = lane & 15, g = lane >> 4;

  const __bf16* qTn = qT + (size_t)n * SS * 4096;
  const __bf16* kTn = kT + (size_t)n * SS * 4096;
  const __bf16* vn  = vv + (size_t)n * 4096 * SS;
  __bf16* yTn = yT + (size_t)n * SS * 4096;

  const int qrow0 = qt * 64 + wave * 16;

  __shared__ __bf16 kbuf[32 * 512];
  __shared__ __bf16 vbuf[512 * 32];
  __shared__ __bf16 pbuf[4 * 16 * 88];
  __shared__ float axs[64];
  __shared__ float ils[64];
  __shared__ int sfl[4];  // per-wave "skipped rescale" flag (T13)

  bf16x8 qf[16];
  {
    const __bf16* qp = qTn + (size_t)(qrow0 + colv) * 4096 + h * 512 + g * 8;
#pragma unroll
    for (int kc = 0; kc < 16; ++kc) qf[kc] = *(const bf16x8*)(qp + kc * 32);
  }

  floatx4 Oacc[32];
#pragma unroll
  for (int t = 0; t < 32; ++t) Oacc[t] = (floatx4)0.f;
  float mrun[4] = {-1e30f, -1e30f, -1e30f, -1e30f};
  float lrun[4] = {0.f, 0.f, 0.f, 0.f};

  __bf16* pb = pbuf + wave * (16 * 88);

  auto stageK = [&](int kt) {
    const int key0 = kt * 32;
#pragma unroll
    for (int j = 0; j < 8; ++j) {
      int row = wave * 8 + j;
      const __bf16* src = kTn + (size_t)(key0 + row) * 4096 + h * 512 + ((lane ^ (row & 7)) << 3);
      async16(src, &kbuf[row * 512]);
    }
  };
  auto stageV = [&](int kt) {
    const int key0 = kt * 32;
#pragma unroll
    for (int j = 0; j < 8; ++j) {
      int i = wave * 8 + j;
      int row = i * 16 + (lane >> 2);
      int ch = (lane & 3) ^ (row & 3);
      const __bf16* src = vn + (size_t)(h * 512 + row) * SS + key0 + ch * 8;
      async16(src, &vbuf[i * 16 * 32]);
    }
  };

  stageK(0);
  stageV(0);

  for (int kt = 0; kt < 64; ++kt) {
    __syncthreads();  // staged K/V drained & visible

    floatx4 sc[2];
    sc[0] = (floatx4)0.f;
    sc[1] = (floatx4)0.f;
#pragma unroll
    for (int ct = 0; ct < 2; ++ct) {
      int key = ct * 16 + colv;
      const __bf16* kb = &kbuf[key * 512];
      int sw = key & 7;
#pragma unroll
      for (int kc = 0; kc < 16; ++kc) {
        bf16x8 bfr = *(const bf16x8*)(kb + (((kc * 4 + g) ^ sw) << 3));
        sc[ct] = __builtin_amdgcn_mfma_f32_16x16x32_bf16(qf[kc], bfr, sc[ct], 0, 0, 0);
      }
    }

    // T13 defer-max: skip rescale while the tile max grows <= THR=8.
    float p[2][4];
    float mx[4];
    float needs = -1e30f;
#pragma unroll
    for (int i = 0; i < 4; ++i) {
      mx[i] = red_max16(fmaxf(sc[0][i], sc[1][i])) * QK_SCALE;
      needs = fmaxf(needs, mx[i] - mrun[i]);
    }
    const bool skip = __all(needs <= 8.0f);  // wave-uniform
    if (skip) {
#pragma unroll
      for (int i = 0; i < 4; ++i) {
        float rs = 0.f;
#pragma unroll
        for (int ct = 0; ct < 2; ++ct) {
          float pvv = __expf(sc[ct][i] * QK_SCALE - mrun[i]);
          p[ct][i] = pvv;
          rs += pvv;
        }
        lrun[i] += red_sum16(rs);
      }
      if (lane == 0) sfl[wave] = 1;
    } else {
      float alpha[4];
#pragma unroll
      for (int i = 0; i < 4; ++i) {
        float mnew = fmaxf(mrun[i], mx[i]);
        alpha[i] = __expf(mrun[i] - mnew);
        float rs = 0.f;
#pragma unroll
        for (int ct = 0; ct < 2; ++ct) {
          float pvv = __expf(sc[ct][i] * QK_SCALE - mnew);
          p[ct][i] = pvv;
          rs += pvv;
        }
        lrun[i] = lrun[i] * alpha[i] + red_sum16(rs);
        mrun[i] = mnew;
      }
      if (colv == 0) {
        floatx4 av;
#pragma unroll
        for (int i = 0; i < 4; ++i) av[i] = alpha[i];
        *(floatx4*)&axs[wave * 16 + g * 4] = av;
      }
      if (lane == 0) sfl[wave] = 0;
    }
#pragma unroll
    for (int ct = 0; ct < 2; ++ct)
#pragma unroll
      for (int i = 0; i < 4; ++i)
        pb[(g * 4 + i) * 88 + ct * 16 + colv] = (__bf16)p[ct][i];
    __syncthreads();  // P + alpha + flags ready; kbuf reads done

    if (kt < 63) stageK(kt + 1);  // kbuf free during PV

#pragma unroll
    for (int qt4 = 0; qt4 < 4; ++qt4) {
      if (sfl[qt4]) continue;  // owner wave deferred: alpha == 1
      floatx4 av = *(const floatx4*)&axs[qt4 * 16 + g * 4];
#pragma unroll
      for (int dt = 0; dt < 8; ++dt) {
        floatx4 o = Oacc[qt4 * 8 + dt];
#pragma unroll
        for (int i = 0; i < 4; ++i) o[i] *= av[i];
        Oacc[qt4 * 8 + dt] = o;
      }
    }
    bf16x8 pa[4];
#pragma unroll
    for (int qt4 = 0; qt4 < 4; ++qt4)
      pa[qt4] = *(const bf16x8*)&pbuf[qt4 * (16 * 88) + colv * 88 + g * 8];
#pragma unroll
    for (int dt = 0; dt < 8; ++dt) {
      int drow = wave * 128 + dt * 16 + colv;
      bf16x8 vb = *(const bf16x8*)&vbuf[drow * 32 + ((g ^ (drow & 3)) << 3)];
#pragma unroll
      for (int qt4 = 0; qt4 < 4; ++qt4)
        Oacc[qt4 * 8 + dt] = __builtin_amdgcn_mfma_f32_16x16x32_bf16(pa[qt4], vb,
                                                                    Oacc[qt4 * 8 + dt], 0, 0, 0);
    }
    __syncthreads();  // PV reads done -> vbuf free
    if (kt < 63) stageV(kt + 1);
  }

  if (colv == 0) {
    floatx4 lv;
#pragma unroll
    for (int i = 0; i < 4; ++i) lv[i] = 1.f / lrun[i];
    *(floatx4*)&ils[wave * 16 + g * 4] = lv;
  }
  __syncthreads();
#pragma unroll
  for (int qt4 = 0; qt4 < 4; ++qt4) {
    floatx4 lv = *(const floatx4*)&ils[qt4 * 16 + g * 4];
#pragma unroll
    for (int dt = 0; dt < 8; ++dt)
#pragma unroll
      for (int i = 0; i < 4; ++i) {
        size_t idx = (size_t)(qt * 64 + qt4 * 16 + g * 4 + i) * 4096 + h * 512 + wave * 128 +
                     dt * 16 + colv;
        yTn[idx] = (__bf16)(Oacc[qt4 * 8 + dt][i] * lv[i]);
      }
  }
}

// ---------------- fused out GEMM: out[c][s] = input + bo[c] + Wo·y ----------------
// A = WoB (M=512=c rows, K=4096), Bt = yT (N=2048=s rows, K=4096).
// R11: 128(c) x 64(s) tile, grid (4,32,4)=512 blocks (2/CU), 256 threads
// (4 waves 2x2, each 64x32), BK=64, double-buffered 48KB LDS, counted
// vmcnt(6), stores s-contiguous fp32 with residual+bias epilogue.
__global__ void __launch_bounds__(256) gemm_out_fused(const __bf16* __restrict__ Wo,
                                                      const __bf16* __restrict__ yT,
                                                      const float* __restrict__ bo,
                                                      const float* __restrict__ input,
                                                      float* __restrict__ out) {
  __shared__ __bf16 lA[2][128 * 64], lB[2][64 * 64];  // 48 KB
  const int n = blockIdx.z;
  const int m0 = blockIdx.x * 128, n0 = blockIdx.y * 64;
  const __bf16* Bt = yT + (size_t)n * SS * 4096;
  const int tid = threadIdx.x;
  const int wave = tid >> 6, lane = tid & 63;
  const int colv = lane & 15, g = lane >> 4;
  const int wm = wave & 1, wn = wave >> 1;   // 2(M) x 2(N); wave-tile 64x32
  const int lrow = lane >> 3, lch = lane & 7;

  // stage K-tile t: per wave 4 async16 for A + 2 for B (6 vmcnt ticks).
  auto stage = [&](int t, int buf) {
    const int k0 = t * 64;
#pragma unroll
    for (int j = 0; j < 4; ++j) {
      int r = wave * 32 + j * 8 + lrow;
      int ch = lch ^ (r & 7);
      async16(Wo + (size_t)(m0 + r) * 4096 + k0 + ch * 8, &lA[buf][(wave * 32 + j * 8) * 64]);
    }
#pragma unroll
    for (int j = 0; j < 2; ++j) {
      int r = wave * 16 + j * 8 + lrow;
      int ch = lch ^ (r & 7);
      async16(Bt + (size_t)(n0 + r) * 4096 + k0 + ch * 8, &lB[buf][(wave * 16 + j * 8) * 64]);
    }
  };

  floatx4 acc[4][2];
#pragma unroll
  for (int mt = 0; mt < 4; ++mt)
#pragma unroll
    for (int nt = 0; nt < 2; ++nt) acc[mt][nt] = (floatx4)0.f;

  // prologue: tiles 0,1 in flight; wait tile 0 landed (tile 1's 6 stay out).
  stage(0, 0);
  stage(1, 1);
  asm volatile("s_waitcnt vmcnt(6)" ::: "memory");
  __builtin_amdgcn_s_barrier();

  for (int t = 0; t < 64; ++t) {
    const int buf = t & 1;
#pragma unroll
    for (int c = 0; c < 2; ++c) {  // K-half (channels c*32..c*32+31)
      bf16x8 af[4], bf[2];
#pragma unroll
      for (int mt = 0; mt < 4; ++mt) {
        int ra = wm * 64 + mt * 16 + colv;
        af[mt] = *(const bf16x8*)&lA[buf][ra * 64 + (((c * 4 + g) ^ (ra & 7)) << 3)];
      }
#pragma unroll
      for (int nt = 0; nt < 2; ++nt) {
        int rb = wn * 32 + nt * 16 + colv;
        bf[nt] = *(const bf16x8*)&lB[buf][rb * 64 + (((c * 4 + g) ^ (rb & 7)) << 3)];
      }
#pragma unroll
      for (int mt = 0; mt < 4; ++mt)
#pragma unroll
        for (int nt = 0; nt < 2; ++nt)
          acc[mt][nt] =
              __builtin_amdgcn_mfma_f32_16x16x32_bf16(af[mt], bf[nt], acc[mt][nt], 0, 0, 0);
    }
    if (t == 63) break;
    __builtin_amdgcn_s_barrier();  // all reads of buf retired
    if (t < 62) {
      stage(t + 2, buf);           // refill freed buf
      asm volatile("s_waitcnt vmcnt(6)" ::: "memory");  // tile t+1 landed
    } else {  // t == 62
      asm volatile("s_waitcnt vmcnt(0)" ::: "memory");
    }
    __builtin_amdgcn_s_barrier();  // everyone's t+1 landed
  }

  // epilogue: c = m0+wm*64+mt*16+g*4+i ; s = n0+wn*32+nt*16+colv ; fp32 direct
#pragma unroll
  for (int mt = 0; mt < 4; ++mt) {
#pragma unroll
    for (int i = 0; i < 4; ++i) {
      int c = m0 + wm * 64 + mt * 16 + g * 4 + i;
      float bov = bo[c];
      size_t rowb = ((size_t)n * CC + c) * SS;
#pragma unroll
      for (int nt = 0; nt < 2; ++nt) {
        int s = n0 + wn * 32 + nt * 16 + colv;
        out[rowb + s] = acc[mt][nt][i] + bov + input[rowb + s];
      }
    }
  }
}

// ---------------- host launcher ----------------
extern "C" void kernel_launch(void* const* d_in, const int* in_sizes, int n_in,
                              void* d_out, int out_size, void* d_ws, size_t ws_size,
                              hipStream_t stream) {
  const float* input   = (const float*)d_in[0];
  const float* context = (const float*)d_in[1];
  const float* gamma   = (const float*)d_in[2];
  const float* beta    = (const float*)d_in[3];
  const float* Wq      = (const float*)d_in[4];
  const float* bq      = (const float*)d_in[5];
  const float* Wkv     = (const float*)d_in[6];
  const float* bkv     = (const float*)d_in[7];
  const float* Wo      = (const float*)d_in[8];
  const float* bo      = (const float*)d_in[9];
  float* out = (float*)d_out;
  (void)in_sizes; (void)n_in; (void)out_size;

  char* ws = (char*)d_ws;
  size_t off = 0;
  auto alloc = [&](size_t b) {
    void* p = ws + off;
    off = (off + b + 255) & ~(size_t)255;
    return p;
  };
  float*  lnp  = (float*)alloc((size_t)4 * 128 * 2 * sizeof(float));
  __bf16* WqB  = (__bf16*)alloc((size_t)4096 * 512 * 2);
  __bf16* WkvB = (__bf16*)alloc((size_t)8192 * 512 * 2);
  __bf16* WoB  = (__bf16*)alloc((size_t)512 * 4096 * 2);
  __bf16* xnT  = (__bf16*)alloc((size_t)NB * SS * CC * 2);
  __bf16* ctxT = (__bf16*)alloc((size_t)NB * SS * CC * 2);

  const size_t PB = (size_t)SS * 4096 * 2;  // 16 MB per batch of q/k/v/y

  prep1<<<dim3(512 + 3 * 4096), dim3(256), 0, stream>>>(input, lnp, Wq, WqB, Wkv, WkvB, Wo, WoB);
  transpose_nc<<<dim3(64, 16, 8), dim3(32, 8), 0, stream>>>(input, context, xnT, ctxT, lnp,
                                                            gamma, beta);

  const size_t MiB = 1ull << 20;
  if (ws_size >= off + 16 * PB + 8 * MiB) {
    // Path A: full-batch buffers
    __bf16* qTb = (__bf16*)alloc(NB * PB);
    __bf16* kTb = (__bf16*)alloc(NB * PB);
    __bf16* vB  = (__bf16*)alloc(NB * PB);
    __bf16* yTb = (__bf16*)alloc(NB * PB);
    gemm_qkv<<<dim3(96, 16, 4), dim3(256), 0, stream>>>(WqB, WkvB, xnT, ctxT, bq, bkv, qTb, kTb,
                                                        vB);
    flash_attn<<<dim3(32, 8, 4), dim3(256), 0, stream>>>(qTb, kTb, vB, yTb);
    gemm_out_fused<<<dim3(4, 32, 4), dim3(256), 0, stream>>>(WoB, yTb, bo, input, out);
  } else if (ws_size >= off + 7 * PB + 8 * MiB) {
    // Path B: per-batch q/k/v, full yT
    __bf16* qTb = (__bf16*)alloc(PB);
    __bf16* kTb = (__bf16*)alloc(PB);
    __bf16* vB  = (__bf16*)alloc(PB);
    __bf16* yTb = (__bf16*)alloc(NB * PB);
    for (int n = 0; n < NB; ++n) {
      gemm_qkv<<<dim3(96, 16, 1), dim3(256), 0, stream>>>(WqB, WkvB, xnT + (size_t)n * SS * CC,
                                                          ctxT + (size_t)n * SS * CC, bq, bkv,
                                                          qTb, kTb, vB);
      flash_attn<<<dim3(32, 8, 1), dim3(256), 0, stream>>>(qTb, kTb, vB,
                                                           yTb + (size_t)n * SS * 4096);
    }
    gemm_out_fused<<<dim3(4, 32, 4), dim3(256), 0, stream>>>(WoB, yTb, bo, input, out);
  } else {
    // Path C: everything per-batch
    __bf16* qTb = (__bf16*)alloc(PB);
    __bf16* kTb = (__bf16*)alloc(PB);
    __bf16* vB  = (__bf16*)alloc(PB);
    __bf16* yTb = (__bf16*)alloc(PB);
    for (int n = 0; n < NB; ++n) {
      gemm_qkv<<<dim3(96, 16, 1), dim3(256), 0, stream>>>(WqB, WkvB, xnT + (size_t)n * SS * CC,
                                                          ctxT + (size_t)n * SS * CC, bq, bkv,
                                                          qTb, kTb, vB);
      flash_attn<<<dim3(32, 8, 1), dim3(256), 0, stream>>>(qTb, kTb, vB, yTb);
      gemm_out_fused<<<dim3(4, 32, 1), dim3(256), 0, stream>>>(WoB, yTb, bo,
                                                               input + (size_t)n * CC * SS,
                                                               out + (size_t)n * CC * SS);
    }
  }
}